// Round 1
// baseline (14371.176 us; speedup 1.0000x reference)
//
#include <hip/hip_runtime.h>
#include <math.h>

#define B_   64
#define S_   3072
#define DIN  128
#define E_   64
#define H_   256
#define OUT_ 10
#define T_   1024
#define NG   16      // batch groups
#define GB   4       // batches per group
#define NCH  8       // chunk-WGs per group (gate split)
#define ROWS 128     // gate rows per WG (4H / NCH)

// workspace layout (bytes)
#define ACT_BYTES  (B_*E_*T_*4)               // actT[b][e][t] fp32 = 16 MB
#define HBUF_OFF   ACT_BYTES
#define HBUF_BYTES (NG*2*GB*H_*4)             // [g][parity][b][256]
#define FLAG_OFF   (HBUF_OFF + HBUF_BYTES)
#define FLAG_BYTES (NG*NCH*4)

// ---------------------------------------------------------------------------
// Conv: normalize rows (per s over D=128), conv1d k=3 stride=3 (non-overlap),
// +bias, relu. Block: 512 thr = 8 waves; block handles (b, 64 t's).
// wave = e-octet, lane = t. x staged in LDS (XOR-swizzled), weights via
// wave-uniform scalar loads. Output actT[b][e][t] (coalesced stores).
// ---------------------------------------------------------------------------
__global__ __launch_bounds__(512, 1) void conv_kernel(
    const float* __restrict__ in,     // [B][S][DIN]
    const float* __restrict__ cw,     // [E][DIN][3]
    const float* __restrict__ cb,     // [E]
    float* __restrict__ actT)         // [B][E][T]
{
  extern __shared__ float xs[];                 // 192 rows x 128 f, swizzled
  float4* xs4 = (float4*)xs;
  const int bid = blockIdx.x;
  const int b  = bid >> 4;
  const int tb = bid & 15;
  const int tid = threadIdx.x;

  // stage 192x128 floats, swizzle 16B-unit index: u = r*32 + (dq ^ (r&7))
  const float4* gin = (const float4*)(in + (size_t)b*S_*DIN + (size_t)tb*192*DIN);
  #pragma unroll
  for (int i = 0; i < 12; ++i) {
    int f4 = tid + i*512;
    int r = f4 >> 5, dq = f4 & 31;
    xs4[r*32 + (dq ^ (r & 7))] = gin[f4];
  }
  __syncthreads();

  // normalize each row (L2 over 128, eps 1e-12)
  const int wv = tid >> 6, ln = tid & 63;
  for (int rr = 0; rr < 24; ++rr) {
    int r = wv*24 + rr;
    int u = r*32 + ((ln >> 1) ^ (r & 7));
    float2* p = (float2*)((char*)xs + (size_t)u*16 + (size_t)(ln & 1)*8);
    float2 v = *p;
    float s = v.x*v.x + v.y*v.y;
    #pragma unroll
    for (int off = 32; off >= 1; off >>= 1) s += __shfl_xor(s, off);
    float inv = 1.0f / fmaxf(sqrtf(s), 1e-12f);
    v.x *= inv; v.y *= inv;
    *p = v;
  }
  __syncthreads();

  // compute: wave -> e-octet (uniform), lane -> local t
  const int eo = __builtin_amdgcn_readfirstlane(wv);
  float acc[8];
  #pragma unroll
  for (int j = 0; j < 8; ++j) acc[j] = cb[eo*8 + j];

  const int r0 = 3*ln, r1 = 3*ln + 1, r2 = 3*ln + 2;
  #pragma unroll 4
  for (int dq = 0; dq < 32; ++dq) {
    float4 x0 = xs4[r0*32 + (dq ^ (r0 & 7))];
    float4 x1 = xs4[r1*32 + (dq ^ (r1 & 7))];
    float4 x2 = xs4[r2*32 + (dq ^ (r2 & 7))];
    #pragma unroll
    for (int j = 0; j < 8; ++j) {
      const float* wp = cw + (size_t)(eo*8 + j)*(DIN*3) + dq*12;  // uniform -> s_load
      acc[j] += x0.x*wp[0] + x1.x*wp[1] + x2.x*wp[2]
              + x0.y*wp[3] + x1.y*wp[4] + x2.y*wp[5]
              + x0.z*wp[6] + x1.z*wp[7] + x2.z*wp[8]
              + x0.w*wp[9] + x1.w*wp[10] + x2.w*wp[11];
    }
  }

  const int tg = tb*64 + ln;
  #pragma unroll
  for (int j = 0; j < 8; ++j) {
    int e = eo*8 + j;
    actT[(size_t)b*E_*T_ + (size_t)e*T_ + tg] = fmaxf(acc[j], 0.0f);
  }
}

// ---------------------------------------------------------------------------
// LSTM: 128 WGs. Group g = bid&15 (batches 4g..4g+3), chunk q = bid>>4
// (h-indices [32q,32q+32), gate rows {m*256+32q+hh}). Weights in VGPRs:
// thread (l2=tid&63, kq=tid>>6) holds rows l2 and l2+64, k-slice [64kq,+64).
// h exchanged per step via global hbuf + agent-scope flags (monotonic).
// ---------------------------------------------------------------------------
__global__ __launch_bounds__(256, 1) void lstm_kernel(
    const float* __restrict__ actT,   // [B][E][T]
    const float* __restrict__ w_ih,   // [1024][64]
    const float* __restrict__ w_hh,   // [1024][256]
    const float* __restrict__ b_ih,
    const float* __restrict__ b_hh,
    float* __restrict__ hbuf,         // [NG][2][GB*H]
    unsigned int* __restrict__ flags) // [NG][NCH]
{
  __shared__ float h_lds[GB][H_];
  __shared__ float x_lds[GB][E_];
  __shared__ float scratch[4][ROWS][GB];
  __shared__ float bias_lds[ROWS];

  const int bid = blockIdx.x;
  const int g = bid & 15;
  const int q = bid >> 4;
  const int tid = threadIdx.x;
  const int l2 = tid & 63;         // row pair base
  const int kq = tid >> 6;         // k quarter

  const int ra = l2, rb = l2 + 64; // local rows (0..127)
  const int growa = (ra >> 5)*256 + 32*q + (ra & 31);
  const int growb = (rb >> 5)*256 + 32*q + (rb & 31);

  // weights -> registers (static-indexed arrays)
  float4 wr0[16], wr1[16], wi0[4], wi1[4];
  {
    const float4* pa = (const float4*)(w_hh + (size_t)growa*H_ + kq*64);
    const float4* pb = (const float4*)(w_hh + (size_t)growb*H_ + kq*64);
    #pragma unroll
    for (int i = 0; i < 16; ++i) { wr0[i] = pa[i]; wr1[i] = pb[i]; }
    const float4* qa = (const float4*)(w_ih + (size_t)growa*E_ + kq*16);
    const float4* qb = (const float4*)(w_ih + (size_t)growb*E_ + kq*16);
    #pragma unroll
    for (int i = 0; i < 4; ++i) { wi0[i] = qa[i]; wi1[i] = qb[i]; }
  }
  if (kq == 0) {
    bias_lds[ra] = b_ih[growa] + b_hh[growa];
    bias_lds[rb] = b_ih[growb] + b_hh[growb];
  }
  #pragma unroll
  for (int i = 0; i < 4; ++i) ((float*)h_lds)[tid + i*256] = 0.0f;

  float c = 0.0f;                        // state for update threads (tid<128)
  const int ub = tid >> 5, uh = tid & 31;
  unsigned int* myflags = flags + g*NCH;
  float* hb = hbuf + (size_t)g*2*GB*H_;
  const int xb = tid >> 6, xe = tid & 63;
  const float* actp = actT + (size_t)(g*GB + xb)*E_*T_ + (size_t)xe*T_;
  const int lane = tid & 63;

  for (int t = 0; t < T_; ++t) {
    float xval = actp[t];               // issue early (no h dependency)
    if (t > 0) {
      const unsigned int tgt = (unsigned)t;
      for (;;) {
        unsigned int v = 0xFFFFFFFFu;
        if (lane < NCH)
          v = __hip_atomic_load(myflags + lane, __ATOMIC_RELAXED, __HIP_MEMORY_SCOPE_AGENT);
        if (!__any(v < tgt)) break;
        __builtin_amdgcn_s_sleep(2);
      }
      __threadfence();                  // acquire: invalidate L1
      const float* src = hb + (size_t)(t & 1)*(GB*H_);
      #pragma unroll
      for (int i = 0; i < 4; ++i) ((float*)h_lds)[tid + i*256] = src[tid + i*256];
    }
    x_lds[xb][xe] = xval;
    __syncthreads();

    // gate partials: rows ra,rb over k in [64kq, 64kq+64)
    float a0=0.f,a1=0.f,a2=0.f,a3=0.f, b0=0.f,b1=0.f,b2=0.f,b3=0.f;
    const float* hp = &h_lds[0][0] + kq*64;
    #pragma unroll
    for (int i = 0; i < 16; ++i) {
      float4 w0 = wr0[i], w1 = wr1[i];
      float4 h0 = *(const float4*)(hp + 0*H_ + i*4);
      float4 h1 = *(const float4*)(hp + 1*H_ + i*4);
      float4 h2 = *(const float4*)(hp + 2*H_ + i*4);
      float4 h3 = *(const float4*)(hp + 3*H_ + i*4);
      a0 += w0.x*h0.x + w0.y*h0.y + w0.z*h0.z + w0.w*h0.w;
      a1 += w0.x*h1.x + w0.y*h1.y + w0.z*h1.z + w0.w*h1.w;
      a2 += w0.x*h2.x + w0.y*h2.y + w0.z*h2.z + w0.w*h2.w;
      a3 += w0.x*h3.x + w0.y*h3.y + w0.z*h3.z + w0.w*h3.w;
      b0 += w1.x*h0.x + w1.y*h0.y + w1.z*h0.z + w1.w*h0.w;
      b1 += w1.x*h1.x + w1.y*h1.y + w1.z*h1.z + w1.w*h1.w;
      b2 += w1.x*h2.x + w1.y*h2.y + w1.z*h2.z + w1.w*h2.w;
      b3 += w1.x*h3.x + w1.y*h3.y + w1.z*h3.z + w1.w*h3.w;
    }
    const float* xp = &x_lds[0][0] + kq*16;
    #pragma unroll
    for (int i = 0; i < 4; ++i) {
      float4 w0 = wi0[i], w1 = wi1[i];
      float4 h0 = *(const float4*)(xp + 0*E_ + i*4);
      float4 h1 = *(const float4*)(xp + 1*E_ + i*4);
      float4 h2 = *(const float4*)(xp + 2*E_ + i*4);
      float4 h3 = *(const float4*)(xp + 3*E_ + i*4);
      a0 += w0.x*h0.x + w0.y*h0.y + w0.z*h0.z + w0.w*h0.w;
      a1 += w0.x*h1.x + w0.y*h1.y + w0.z*h1.z + w0.w*h1.w;
      a2 += w0.x*h2.x + w0.y*h2.y + w0.z*h2.z + w0.w*h2.w;
      a3 += w0.x*h3.x + w0.y*h3.y + w0.z*h3.z + w0.w*h3.w;
      b0 += w1.x*h0.x + w1.y*h0.y + w1.z*h0.z + w1.w*h0.w;
      b1 += w1.x*h1.x + w1.y*h1.y + w1.z*h1.z + w1.w*h1.w;
      b2 += w1.x*h2.x + w1.y*h2.y + w1.z*h2.z + w1.w*h2.w;
      b3 += w1.x*h3.x + w1.y*h3.y + w1.z*h3.z + w1.w*h3.w;
    }
    *(float4*)&scratch[kq][ra][0] = make_float4(a0, a1, a2, a3);
    *(float4*)&scratch[kq][rb][0] = make_float4(b0, b1, b2, b3);
    __syncthreads();

    if (tid < 128) {
      float gi = bias_lds[uh],      gf = bias_lds[32+uh];
      float gg = bias_lds[64+uh],   go = bias_lds[96+uh];
      #pragma unroll
      for (int k = 0; k < 4; ++k) {
        gi += scratch[k][uh][ub];
        gf += scratch[k][32+uh][ub];
        gg += scratch[k][64+uh][ub];
        go += scratch[k][96+uh][ub];
      }
      float si = 1.0f/(1.0f + expf(-gi));
      float sf = 1.0f/(1.0f + expf(-gf));
      float so = 1.0f/(1.0f + expf(-go));
      c = sf*c + si*tanhf(gg);
      float h = so*tanhf(c);
      hb[(size_t)((t+1) & 1)*(GB*H_) + (size_t)ub*H_ + 32*q + uh] = h;
    }
    __syncthreads();                    // drains vmem stores before flag
    if (tid == 0) {
      __threadfence();
      __hip_atomic_store(myflags + q, (unsigned)(t+1), __ATOMIC_RELAXED, __HIP_MEMORY_SCOPE_AGENT);
    }
  }
}

// ---------------------------------------------------------------------------
// Head: out[b][o] = h_last[b] . lin_w[o] + lin_b[o]
// ---------------------------------------------------------------------------
__global__ void head_kernel(const float* __restrict__ hbuf,
                            const float* __restrict__ lw,
                            const float* __restrict__ lb,
                            float* __restrict__ out)
{
  int idx = blockIdx.x*blockDim.x + threadIdx.x;
  if (idx >= B_*OUT_) return;
  int b = idx / OUT_, o = idx % OUT_;
  int g = b >> 2, bl = b & 3;
  // h_state[1024] parity = 0
  const float* h = hbuf + (size_t)g*2*GB*H_ + (size_t)bl*H_;
  const float* w = lw + (size_t)o*H_;
  float s = lb[o];
  #pragma unroll 8
  for (int k = 0; k < H_; ++k) s += h[k]*w[k];
  out[idx] = s;
}

extern "C" void kernel_launch(void* const* d_in, const int* in_sizes, int n_in,
                              void* d_out, int out_size, void* d_ws, size_t ws_size,
                              hipStream_t stream) {
  const float* inputs = (const float*)d_in[0];
  // d_in[1] = r (unused), d_in[2] = batch_size (unused)
  const float* conv_w = (const float*)d_in[3];
  const float* conv_b = (const float*)d_in[4];
  const float* w_ih   = (const float*)d_in[5];
  const float* w_hh   = (const float*)d_in[6];
  const float* b_ih   = (const float*)d_in[7];
  const float* b_hh   = (const float*)d_in[8];
  const float* lin_w  = (const float*)d_in[9];
  const float* lin_b  = (const float*)d_in[10];

  float* actT = (float*)d_ws;
  float* hbuf = (float*)((char*)d_ws + HBUF_OFF);
  unsigned int* flags = (unsigned int*)((char*)d_ws + FLAG_OFF);

  hipMemsetAsync(flags, 0, FLAG_BYTES, stream);
  hipLaunchKernelGGL(conv_kernel, dim3(B_*16), dim3(512), 192*128*4, stream,
                     inputs, conv_w, conv_b, actT);
  hipLaunchKernelGGL(lstm_kernel, dim3(NG*NCH), dim3(256), 0, stream,
                     actT, w_ih, w_hh, b_ih, b_hh, hbuf, flags);
  hipLaunchKernelGGL(head_kernel, dim3(3), dim3(256), 0, stream,
                     hbuf, lin_w, lin_b, (float*)d_out);
}

// Round 2
// 4470.783 us; speedup vs baseline: 3.2145x; 3.2145x over previous
//
#include <hip/hip_runtime.h>
#include <math.h>

#define B_   64
#define S_   3072
#define DIN  128
#define E_   64
#define H_   256
#define OUT_ 10
#define T_   1024
#define NG   16      // batch groups
#define GB   4       // batches per group
#define NCH  8       // chunk-WGs per group (gate split)
#define ROWS 128     // gate rows per WG (4H / NCH)
#define GBH  (GB*H_)

// workspace layout (bytes)
#define ACT_BYTES  (B_*E_*T_*4)               // actT[b][e][t] fp32 = 16 MB
#define HBUF_OFF   ACT_BYTES
#define HBUF_BYTES (NG*2*GBH*4)               // [g][parity][b][256]
#define FLAG_OFF   (HBUF_OFF + HBUF_BYTES)
#define FLAG_BYTES (NG*NCH*4)

typedef float f32x4 __attribute__((ext_vector_type(4)));

// --- coherent (cross-XCD, fence-free) access helpers: sc0 sc1 = bypass L1+L2,
// --- serviced at the Infinity-Fabric coherence point. No buffer_inv/wbl2.
__device__ __forceinline__ void store_f32_cohere(float* p, float v) {
  asm volatile("global_store_dword %0, %1, off sc0 sc1" :: "v"(p), "v"(v) : "memory");
}
__device__ __forceinline__ f32x4 load_f32x4_cohere(const float* p) {
  f32x4 r;
  asm volatile("global_load_dwordx4 %0, %1, off sc0 sc1\n\ts_waitcnt vmcnt(0)"
               : "=v"(r) : "v"(p) : "memory");
  return r;
}
__device__ __forceinline__ unsigned load_u32_cohere(const unsigned* p) {
  unsigned r;
  asm volatile("global_load_dword %0, %1, off sc0 sc1\n\ts_waitcnt vmcnt(0)"
               : "=v"(r) : "v"(p) : "memory");
  return r;
}
__device__ __forceinline__ void store_u32_cohere(unsigned* p, unsigned v) {
  asm volatile("global_store_dword %0, %1, off sc0 sc1" :: "v"(p), "v"(v) : "memory");
}
__device__ __forceinline__ void waitcnt_vm0() {
  asm volatile("s_waitcnt vmcnt(0)" ::: "memory");
}

// ---------------------------------------------------------------------------
// Conv: normalize rows (per s over D=128), conv1d k=3 stride=3 (non-overlap),
// +bias, relu. Block: 512 thr = 8 waves; block handles (b, 64 t's).
// ---------------------------------------------------------------------------
__global__ __launch_bounds__(512, 1) void conv_kernel(
    const float* __restrict__ in,     // [B][S][DIN]
    const float* __restrict__ cw,     // [E][DIN][3]
    const float* __restrict__ cb,     // [E]
    float* __restrict__ actT)         // [B][E][T]
{
  extern __shared__ float xs[];                 // 192 rows x 128 f, swizzled
  float4* xs4 = (float4*)xs;
  const int bid = blockIdx.x;
  const int b  = bid >> 4;
  const int tb = bid & 15;
  const int tid = threadIdx.x;

  const float4* gin = (const float4*)(in + (size_t)b*S_*DIN + (size_t)tb*192*DIN);
  #pragma unroll
  for (int i = 0; i < 12; ++i) {
    int f4 = tid + i*512;
    int r = f4 >> 5, dq = f4 & 31;
    xs4[r*32 + (dq ^ (r & 7))] = gin[f4];
  }
  __syncthreads();

  const int wv = tid >> 6, ln = tid & 63;
  for (int rr = 0; rr < 24; ++rr) {
    int r = wv*24 + rr;
    int u = r*32 + ((ln >> 1) ^ (r & 7));
    float2* p = (float2*)((char*)xs + (size_t)u*16 + (size_t)(ln & 1)*8);
    float2 v = *p;
    float s = v.x*v.x + v.y*v.y;
    #pragma unroll
    for (int off = 32; off >= 1; off >>= 1) s += __shfl_xor(s, off);
    float inv = 1.0f / fmaxf(sqrtf(s), 1e-12f);
    v.x *= inv; v.y *= inv;
    *p = v;
  }
  __syncthreads();

  const int eo = __builtin_amdgcn_readfirstlane(wv);
  float acc[8];
  #pragma unroll
  for (int j = 0; j < 8; ++j) acc[j] = cb[eo*8 + j];

  const int r0 = 3*ln, r1 = 3*ln + 1, r2 = 3*ln + 2;
  #pragma unroll 4
  for (int dq = 0; dq < 32; ++dq) {
    float4 x0 = xs4[r0*32 + (dq ^ (r0 & 7))];
    float4 x1 = xs4[r1*32 + (dq ^ (r1 & 7))];
    float4 x2 = xs4[r2*32 + (dq ^ (r2 & 7))];
    #pragma unroll
    for (int j = 0; j < 8; ++j) {
      const float* wp = cw + (size_t)(eo*8 + j)*(DIN*3) + dq*12;  // uniform
      acc[j] += x0.x*wp[0] + x1.x*wp[1] + x2.x*wp[2]
              + x0.y*wp[3] + x1.y*wp[4] + x2.y*wp[5]
              + x0.z*wp[6] + x1.z*wp[7] + x2.z*wp[8]
              + x0.w*wp[9] + x1.w*wp[10] + x2.w*wp[11];
    }
  }

  const int tg = tb*64 + ln;
  #pragma unroll
  for (int j = 0; j < 8; ++j) {
    int e = eo*8 + j;
    actT[(size_t)b*E_*T_ + (size_t)e*T_ + tg] = fmaxf(acc[j], 0.0f);
  }
}

// ---------------------------------------------------------------------------
// LSTM: 128 WGs. Group g = bid&15 (batches 4g..4g+3), chunk q = bid>>4
// (gate rows {m*256+32q+hh}). Weights resident in VGPRs. h exchanged per step
// through IF-coherent loads/stores (sc0 sc1) + monotonic flags. No fences.
// ---------------------------------------------------------------------------
__global__ __launch_bounds__(256, 1) void lstm_kernel(
    const float* __restrict__ actT,   // [B][E][T]
    const float* __restrict__ w_ih,   // [1024][64]
    const float* __restrict__ w_hh,   // [1024][256]
    const float* __restrict__ b_ih,
    const float* __restrict__ b_hh,
    float* hbuf,                      // [NG][2][GB*H]
    unsigned int* flags)              // [NG][NCH]
{
  __shared__ float h_lds[GB][H_];
  __shared__ float x_lds[GB][E_];
  __shared__ float scratch[4][ROWS][GB];
  __shared__ float bias_lds[ROWS];

  const int bid = blockIdx.x;
  const int g = bid & 15;
  const int q = bid >> 4;
  const int tid = threadIdx.x;
  const int l2 = tid & 63;         // row pair base
  const int kq = tid >> 6;         // k quarter (= wave id)

  const int ra = l2, rb = l2 + 64; // local rows (0..127)
  const int growa = (ra >> 5)*256 + 32*q + (ra & 31);
  const int growb = (rb >> 5)*256 + 32*q + (rb & 31);

  // weights -> registers
  float4 wr0[16], wr1[16], wi0[4], wi1[4];
  {
    const float4* pa = (const float4*)(w_hh + (size_t)growa*H_ + kq*64);
    const float4* pb = (const float4*)(w_hh + (size_t)growb*H_ + kq*64);
    #pragma unroll
    for (int i = 0; i < 16; ++i) { wr0[i] = pa[i]; wr1[i] = pb[i]; }
    const float4* qa = (const float4*)(w_ih + (size_t)growa*E_ + kq*16);
    const float4* qb = (const float4*)(w_ih + (size_t)growb*E_ + kq*16);
    #pragma unroll
    for (int i = 0; i < 4; ++i) { wi0[i] = qa[i]; wi1[i] = qb[i]; }
  }
  if (kq == 0) {
    bias_lds[ra] = b_ih[growa] + b_hh[growa];
    bias_lds[rb] = b_ih[growb] + b_hh[growb];
  }
  #pragma unroll
  for (int i = 0; i < 4; ++i) ((float*)h_lds)[tid + i*256] = 0.0f;

  float c = 0.0f;                        // cell state (tid<128 threads)
  const int ub = tid >> 5, uh = tid & 31;
  unsigned int* myflags = flags + g*NCH;
  float* hb = hbuf + (size_t)g*2*GBH;
  const int xb = tid >> 6, xe = tid & 63;
  const float* actp = actT + (size_t)(g*GB + xb)*E_*T_ + (size_t)xe*T_;
  const int lane = tid & 63;

  // x[0] into LDS
  float xnext = actp[0];
  x_lds[xb][xe] = xnext;
  __syncthreads();

  for (int t = 0; t < T_; ++t) {
    // ---- A: x-gate partials (no h dependency; runs while flags propagate)
    float a0=0.f,a1=0.f,a2=0.f,a3=0.f, b0=0.f,b1=0.f,b2=0.f,b3=0.f;
    {
      const float* xp = &x_lds[0][0] + kq*16;
      #pragma unroll
      for (int i = 0; i < 4; ++i) {
        float4 w0 = wi0[i], w1 = wi1[i];
        float4 h0 = *(const float4*)(xp + 0*E_ + i*4);
        float4 h1 = *(const float4*)(xp + 1*E_ + i*4);
        float4 h2 = *(const float4*)(xp + 2*E_ + i*4);
        float4 h3 = *(const float4*)(xp + 3*E_ + i*4);
        a0 += w0.x*h0.x + w0.y*h0.y + w0.z*h0.z + w0.w*h0.w;
        a1 += w0.x*h1.x + w0.y*h1.y + w0.z*h1.z + w0.w*h1.w;
        a2 += w0.x*h2.x + w0.y*h2.y + w0.z*h2.z + w0.w*h2.w;
        a3 += w0.x*h3.x + w0.y*h3.y + w0.z*h3.z + w0.w*h3.w;
        b0 += w1.x*h0.x + w1.y*h0.y + w1.z*h0.z + w1.w*h0.w;
        b1 += w1.x*h1.x + w1.y*h1.y + w1.z*h1.z + w1.w*h1.w;
        b2 += w1.x*h2.x + w1.y*h2.y + w1.z*h2.z + w1.w*h2.w;
        b3 += w1.x*h3.x + w1.y*h3.y + w1.z*h3.z + w1.w*h3.w;
      }
    }
    // prefetch next x (plain load, stays in flight through the poll)
    float xpre = actp[(t + 1 < T_) ? (t + 1) : t];

    // ---- B: wait for all chunks of h[t], fetch coherently
    if (t > 0) {
      const unsigned int tgt = (unsigned)t;
      for (;;) {
        unsigned int v = 0xFFFFFFFFu;
        if (lane < NCH) v = load_u32_cohere(myflags + lane);
        if (!__any(v < tgt)) break;
        __builtin_amdgcn_s_sleep(1);
      }
      f32x4 hv = load_f32x4_cohere(hb + (size_t)(t & 1)*GBH + tid*4);
      *(f32x4*)&((float*)h_lds)[tid*4] = hv;
    }
    __syncthreads();   // C: h_lds ready

    // ---- D: h-gate partials, rows ra,rb over k in [64kq, 64kq+64)
    {
      const float* hp = &h_lds[0][0] + kq*64;
      #pragma unroll
      for (int i = 0; i < 16; ++i) {
        float4 w0 = wr0[i], w1 = wr1[i];
        float4 h0 = *(const float4*)(hp + 0*H_ + i*4);
        float4 h1 = *(const float4*)(hp + 1*H_ + i*4);
        float4 h2 = *(const float4*)(hp + 2*H_ + i*4);
        float4 h3 = *(const float4*)(hp + 3*H_ + i*4);
        a0 += w0.x*h0.x + w0.y*h0.y + w0.z*h0.z + w0.w*h0.w;
        a1 += w0.x*h1.x + w0.y*h1.y + w0.z*h1.z + w0.w*h1.w;
        a2 += w0.x*h2.x + w0.y*h2.y + w0.z*h2.z + w0.w*h2.w;
        a3 += w0.x*h3.x + w0.y*h3.y + w0.z*h3.z + w0.w*h3.w;
        b0 += w1.x*h0.x + w1.y*h0.y + w1.z*h0.z + w1.w*h0.w;
        b1 += w1.x*h1.x + w1.y*h1.y + w1.z*h1.z + w1.w*h1.w;
        b2 += w1.x*h2.x + w1.y*h2.y + w1.z*h2.z + w1.w*h2.w;
        b3 += w1.x*h3.x + w1.y*h3.y + w1.z*h3.z + w1.w*h3.w;
      }
    }
    *(float4*)&scratch[kq][ra][0] = make_float4(a0, a1, a2, a3);
    *(float4*)&scratch[kq][rb][0] = make_float4(b0, b1, b2, b3);
    __syncthreads();   // E: partials ready

    // ---- F: gate reduce + nonlinearities + state update (tid<128)
    if (tid < 128) {
      float gi = bias_lds[uh],      gf = bias_lds[32+uh];
      float gg = bias_lds[64+uh],   go = bias_lds[96+uh];
      #pragma unroll
      for (int k = 0; k < 4; ++k) {
        gi += scratch[k][uh][ub];
        gf += scratch[k][32+uh][ub];
        gg += scratch[k][64+uh][ub];
        go += scratch[k][96+uh][ub];
      }
      float si = 1.0f/(1.0f + expf(-gi));
      float sf = 1.0f/(1.0f + expf(-gf));
      float so = 1.0f/(1.0f + expf(-go));
      c = sf*c + si*tanhf(gg);
      float h = so*tanhf(c);
      store_f32_cohere(hb + (size_t)((t+1) & 1)*GBH + (size_t)ub*H_ + 32*q + uh, h);
      waitcnt_vm0();   // h globally visible before flag (after barrier)
    }
    x_lds[xb][xe] = xpre;
    __syncthreads();   // G
    if (tid == 0) store_u32_cohere(myflags + q, (unsigned)(t+1));
  }
}

// ---------------------------------------------------------------------------
// Head: out[b][o] = h_last[b] . lin_w[o] + lin_b[o]
// ---------------------------------------------------------------------------
__global__ void head_kernel(const float* __restrict__ hbuf,
                            const float* __restrict__ lw,
                            const float* __restrict__ lb,
                            float* __restrict__ out)
{
  int idx = blockIdx.x*blockDim.x + threadIdx.x;
  if (idx >= B_*OUT_) return;
  int b = idx / OUT_, o = idx % OUT_;
  int g = b >> 2, bl = b & 3;
  const float* h = hbuf + (size_t)g*2*GBH + (size_t)bl*H_;  // parity 0
  const float* w = lw + (size_t)o*H_;
  float s = lb[o];
  #pragma unroll 8
  for (int k = 0; k < H_; ++k) s += h[k]*w[k];
  out[idx] = s;
}

extern "C" void kernel_launch(void* const* d_in, const int* in_sizes, int n_in,
                              void* d_out, int out_size, void* d_ws, size_t ws_size,
                              hipStream_t stream) {
  const float* inputs = (const float*)d_in[0];
  const float* conv_w = (const float*)d_in[3];
  const float* conv_b = (const float*)d_in[4];
  const float* w_ih   = (const float*)d_in[5];
  const float* w_hh   = (const float*)d_in[6];
  const float* b_ih   = (const float*)d_in[7];
  const float* b_hh   = (const float*)d_in[8];
  const float* lin_w  = (const float*)d_in[9];
  const float* lin_b  = (const float*)d_in[10];

  float* actT = (float*)d_ws;
  float* hbuf = (float*)((char*)d_ws + HBUF_OFF);
  unsigned int* flags = (unsigned int*)((char*)d_ws + FLAG_OFF);

  hipMemsetAsync(flags, 0, FLAG_BYTES, stream);
  hipLaunchKernelGGL(conv_kernel, dim3(B_*16), dim3(512), 192*128*4, stream,
                     inputs, conv_w, conv_b, actT);
  hipLaunchKernelGGL(lstm_kernel, dim3(NG*NCH), dim3(256), 0, stream,
                     actT, w_ih, w_hh, b_ih, b_hh, hbuf, flags);
  hipLaunchKernelGGL(head_kernel, dim3(3), dim3(256), 0, stream,
                     hbuf, lin_w, lin_b, (float*)d_out);
}

// Round 4
// 2561.967 us; speedup vs baseline: 5.6094x; 1.7451x over previous
//
#include <hip/hip_runtime.h>
#include <math.h>

#define B_   64
#define S_   3072
#define DIN  128
#define E_   64
#define H_   256
#define OUT_ 10
#define T_   1024
#define NG   32      // batch groups
#define GB   2       // batches per group
#define NCH  8       // chunk-WGs per group (gate split)
#define ROWS 128     // gate rows per WG (4H / NCH)
#define GBH  (GB*H_) // 512

#define SLOTS_PER_CHUNK 22           // ceil(64 values / 3 per 16B line)
#define SLOTS_TOTAL     (NCH*SLOTS_PER_CHUNK)   // 176 per group per parity
#define HB_PAR_FLOATS   (SLOTS_TOTAL*4)         // 704
#define HB_GRP_FLOATS   (2*HB_PAR_FLOATS)       // 1408

// workspace layout (bytes)
#define ACT_BYTES   (B_*E_*T_*4)              // actT[b][e][t] fp32 = 16 MB
#define HBUF_OFF    ACT_BYTES
#define HBUF_BYTES  (NG*HB_GRP_FLOATS*4)      // 180224
#define HFINAL_OFF  (HBUF_OFF + 184320)
#define HFINAL_BYTES (NG*GBH*4)               // 64 KB

typedef float f32x4 __attribute__((ext_vector_type(4)));

// IF-coherent access (cross-XCD safe, fence-free). Proven in round 2.
__device__ __forceinline__ f32x4 coh_load_f32x4(const float* p) {
  f32x4 r;
  asm volatile("global_load_dwordx4 %0, %1, off sc0 sc1\n\ts_waitcnt vmcnt(0)"
               : "=v"(r) : "v"(p) : "memory");
  return r;
}
__device__ __forceinline__ void coh_store_f32x4(float* p, f32x4 v) {
  asm volatile("global_store_dwordx4 %0, %1, off sc0 sc1" :: "v"(p), "v"(v) : "memory");
}

__device__ __forceinline__ float fast_sigmoid(float x) {
  return __builtin_amdgcn_rcpf(1.0f + __expf(-x));
}
__device__ __forceinline__ float fast_tanh(float x) {
  return 2.0f * __builtin_amdgcn_rcpf(1.0f + __expf(-2.0f * x)) - 1.0f;
}

// ---------------------------------------------------------------------------
// Conv: normalize rows (L2 over D=128), conv1d k=3 stride=3, +bias, relu.
// ---------------------------------------------------------------------------
__global__ __launch_bounds__(512, 1) void conv_kernel(
    const float* __restrict__ in,     // [B][S][DIN]
    const float* __restrict__ cw,     // [E][DIN][3]
    const float* __restrict__ cb,     // [E]
    float* __restrict__ actT)         // [B][E][T]
{
  extern __shared__ float xs[];                 // 192 rows x 128 f, swizzled
  float4* xs4 = (float4*)xs;
  const int bid = blockIdx.x;
  const int b  = bid >> 4;
  const int tb = bid & 15;
  const int tid = threadIdx.x;

  const float4* gin = (const float4*)(in + (size_t)b*S_*DIN + (size_t)tb*192*DIN);
  #pragma unroll
  for (int i = 0; i < 12; ++i) {
    int f4 = tid + i*512;
    int r = f4 >> 5, dq = f4 & 31;
    xs4[r*32 + (dq ^ (r & 7))] = gin[f4];
  }
  __syncthreads();

  const int wv = tid >> 6, ln = tid & 63;
  for (int rr = 0; rr < 24; ++rr) {
    int r = wv*24 + rr;
    int u = r*32 + ((ln >> 1) ^ (r & 7));
    float2* p = (float2*)((char*)xs + (size_t)u*16 + (size_t)(ln & 1)*8);
    float2 v = *p;
    float s = v.x*v.x + v.y*v.y;
    #pragma unroll
    for (int off = 32; off >= 1; off >>= 1) s += __shfl_xor(s, off);
    float inv = 1.0f / fmaxf(sqrtf(s), 1e-12f);
    v.x *= inv; v.y *= inv;
    *p = v;
  }
  __syncthreads();

  const int eo = __builtin_amdgcn_readfirstlane(wv);
  float acc[8];
  #pragma unroll
  for (int j = 0; j < 8; ++j) acc[j] = cb[eo*8 + j];

  const int r0 = 3*ln, r1 = 3*ln + 1, r2 = 3*ln + 2;
  #pragma unroll 4
  for (int dq = 0; dq < 32; ++dq) {
    float4 x0 = xs4[r0*32 + (dq ^ (r0 & 7))];
    float4 x1 = xs4[r1*32 + (dq ^ (r1 & 7))];
    float4 x2 = xs4[r2*32 + (dq ^ (r2 & 7))];
    #pragma unroll
    for (int j = 0; j < 8; ++j) {
      const float* wp = cw + (size_t)(eo*8 + j)*(DIN*3) + dq*12;  // uniform
      acc[j] += x0.x*wp[0] + x1.x*wp[1] + x2.x*wp[2]
              + x0.y*wp[3] + x1.y*wp[4] + x2.y*wp[5]
              + x0.z*wp[6] + x1.z*wp[7] + x2.z*wp[8]
              + x0.w*wp[9] + x1.w*wp[10] + x2.w*wp[11];
    }
  }

  const int tg = tb*64 + ln;
  #pragma unroll
  for (int j = 0; j < 8; ++j) {
    int e = eo*8 + j;
    actT[(size_t)b*E_*T_ + (size_t)e*T_ + tg] = fmaxf(acc[j], 0.0f);
  }
}

// ---------------------------------------------------------------------------
// LSTM: 256 WGs = 32 groups x 8 chunks. Group g = bid&31 (batches 2g,2g+1),
// chunk q = bid>>5 (gate rows {m*256+32q+hh}). Weights in VGPRs.
// h exchange: 16B lines [h0,h1,h2, stamp] — data+validity in ONE atomic line,
// one sc0sc1 store per line, readers poll the lines directly. No flags,
// no fences, no writer-side waitcnt. Stamp at step t == t (monotone).
// ---------------------------------------------------------------------------
__global__ __launch_bounds__(256, 1) void lstm_kernel(
    const float* __restrict__ actT,   // [B][E][T]
    const float* __restrict__ w_ih,   // [1024][64]
    const float* __restrict__ w_hh,   // [1024][256]
    const float* __restrict__ b_ih,
    const float* __restrict__ b_hh,
    float* hbuf,                      // [NG][2][HB_PAR_FLOATS]
    float* hfinal)                    // [NG][GBH]
{
  __shared__ float h_lds[GBH];              // [GB][H]
  __shared__ float x_lds[GB*E_];            // [GB][E]
  __shared__ float scratch[4][ROWS][GB];
  __shared__ float bias_lds[ROWS];

  const int bid = blockIdx.x;
  const int g = bid & 31;
  const int q = bid >> 5;
  const int tid = threadIdx.x;
  const int lane = tid & 63;
  const int kq = tid >> 6;         // k quarter (= wave id)

  const int ra = lane, rb = lane + 64;      // local rows (0..127)
  const int growa = (ra >> 5)*256 + 32*q + (ra & 31);
  const int growb = (rb >> 5)*256 + 32*q + (rb & 31);

  // weights -> registers
  float4 wr0[16], wr1[16], wi0[4], wi1[4];
  {
    const float4* pa = (const float4*)(w_hh + (size_t)growa*H_ + kq*64);
    const float4* pb = (const float4*)(w_hh + (size_t)growb*H_ + kq*64);
    #pragma unroll
    for (int i = 0; i < 16; ++i) { wr0[i] = pa[i]; wr1[i] = pb[i]; }
    const float4* qa = (const float4*)(w_ih + (size_t)growa*E_ + kq*16);
    const float4* qb = (const float4*)(w_ih + (size_t)growb*E_ + kq*16);
    #pragma unroll
    for (int i = 0; i < 4; ++i) { wi0[i] = qa[i]; wi1[i] = qb[i]; }
  }
  if (kq == 0) {
    bias_lds[ra] = b_ih[growa] + b_hh[growa];
    bias_lds[rb] = b_ih[growb] + b_hh[growb];
  }
  ((float2*)h_lds)[tid] = make_float2(0.0f, 0.0f);

  float* hgrp = hbuf + (size_t)g*HB_GRP_FLOATS;
  const int xb = (tid >> 6) & 1, xe = lane;
  const float* actp = actT + (size_t)(g*GB + xb)*E_*T_ + (size_t)xe*T_;
  const int uh = tid & 31, ub = (tid >> 5) & 1;   // F-phase mapping (tid<64)

  // reader slot mapping (threads 0..175)
  const int sq = tid / SLOTS_PER_CHUNK;     // source chunk
  const int sj = tid % SLOTS_PER_CHUNK;     // slot within chunk
  const int sl = 3*sj;                      // first source lane

  // x[0] into LDS
  if (tid < 128) x_lds[xb*E_ + xe] = actp[0];
  __syncthreads();

  float c = 0.0f;                           // cell state (tid<64)
  for (int t = 0; t < T_; ++t) {
    // ---- A: x-gate partials (no h dependency; fills store-flight time)
    float a0=0.f, a1=0.f, b0=0.f, b1=0.f;
    {
      const float* xp = x_lds + kq*16;
      #pragma unroll
      for (int i = 0; i < 4; ++i) {
        float4 w0 = wi0[i], w1 = wi1[i];
        float4 x0 = *(const float4*)(xp + 0*E_ + i*4);
        float4 x1 = *(const float4*)(xp + 1*E_ + i*4);
        a0 += w0.x*x0.x + w0.y*x0.y + w0.z*x0.z + w0.w*x0.w;
        a1 += w0.x*x1.x + w0.y*x1.y + w0.z*x1.z + w0.w*x1.w;
        b0 += w1.x*x0.x + w1.y*x0.y + w1.z*x0.z + w1.w*x0.w;
        b1 += w1.x*x1.x + w1.y*x1.y + w1.z*x1.z + w1.w*x1.w;
      }
    }
    float xpre = actp[(t + 1 < T_) ? (t + 1) : t];   // prefetch next x

    // ---- B: poll stamped h lines, scatter into h_lds
    if (t > 0 && tid < SLOTS_TOTAL) {
      const float* sp = hgrp + (size_t)(t & 1)*HB_PAR_FLOATS + tid*4;
      f32x4 v;
      for (;;) {
        v = coh_load_f32x4(sp);
        if (__float_as_int(v[3]) == t) break;
      }
      h_lds[((sl    >> 5))*H_ + 32*sq + (sl     & 31)] = v[0];
      if (sl + 1 < 64) h_lds[(((sl+1) >> 5))*H_ + 32*sq + ((sl+1) & 31)] = v[1];
      if (sl + 2 < 64) h_lds[(((sl+2) >> 5))*H_ + 32*sq + ((sl+2) & 31)] = v[2];
    }
    __syncthreads();   // C: h_lds ready

    // ---- D: h-gate partials, rows ra,rb over k in [64kq, 64kq+64)
    {
      const float* hp = h_lds + kq*64;
      #pragma unroll
      for (int i = 0; i < 16; ++i) {
        float4 w0 = wr0[i], w1 = wr1[i];
        float4 h0 = *(const float4*)(hp + 0*H_ + i*4);
        float4 h1 = *(const float4*)(hp + 1*H_ + i*4);
        a0 += w0.x*h0.x + w0.y*h0.y + w0.z*h0.z + w0.w*h0.w;
        a1 += w0.x*h1.x + w0.y*h1.y + w0.z*h1.z + w0.w*h1.w;
        b0 += w1.x*h0.x + w1.y*h0.y + w1.z*h0.z + w1.w*h0.w;
        b1 += w1.x*h1.x + w1.y*h1.y + w1.z*h1.z + w1.w*h1.w;
      }
    }
    *(float2*)&scratch[kq][ra][0] = make_float2(a0, a1);
    *(float2*)&scratch[kq][rb][0] = make_float2(b0, b1);
    __syncthreads();   // E: partials ready

    // ---- F: gate reduce + nonlinearities + state update (1 wave, tid<64)
    if (tid < 64) {
      float gi = bias_lds[uh],      gf = bias_lds[32+uh];
      float gg = bias_lds[64+uh],   go = bias_lds[96+uh];
      #pragma unroll
      for (int k = 0; k < 4; ++k) {
        gi += scratch[k][uh][ub];
        gf += scratch[k][32+uh][ub];
        gg += scratch[k][64+uh][ub];
        go += scratch[k][96+uh][ub];
      }
      float si = fast_sigmoid(gi);
      float sf = fast_sigmoid(gf);
      float so = fast_sigmoid(go);
      c = sf*c + si*fast_tanh(gg);
      float h = so*fast_tanh(c);

      // pack lanes {3j,3j+1,3j+2} -> one stamped 16B line, single coherent store
      int j = lane;
      int s1 = (3*j + 1 < 64) ? 3*j + 1 : 63;
      int s2 = (3*j + 2 < 64) ? 3*j + 2 : 63;
      float v0 = __shfl(h, 3*j, 64);
      float v1 = __shfl(h, s1, 64);
      float v2 = __shfl(h, s2, 64);
      if (j < SLOTS_PER_CHUNK) {
        f32x4 line;
        line[0] = v0; line[1] = v1; line[2] = v2;
        line[3] = __int_as_float(t + 1);
        float* dp = hgrp + (size_t)((t+1) & 1)*HB_PAR_FLOATS
                  + (size_t)(q*SLOTS_PER_CHUNK + j)*4;
        coh_store_f32x4(dp, line);
      }
      if (t == T_ - 1) {
        // plain store; kernel-boundary release makes it visible to head_kernel
        hfinal[(size_t)g*GBH + ub*H_ + 32*q + uh] = h;
      }
    }
    if (tid < 128) x_lds[xb*E_ + xe] = xpre;   // stage next x
    __syncthreads();   // G
  }
}

// ---------------------------------------------------------------------------
// Head: out[b][o] = h_last[b] . lin_w[o] + lin_b[o]
// ---------------------------------------------------------------------------
__global__ void head_kernel(const float* __restrict__ hfinal,
                            const float* __restrict__ lw,
                            const float* __restrict__ lb,
                            float* __restrict__ out)
{
  int idx = blockIdx.x*blockDim.x + threadIdx.x;
  if (idx >= B_*OUT_) return;
  int b = idx / OUT_, o = idx % OUT_;
  int g = b >> 1, bl = b & 1;
  const float* h = hfinal + (size_t)g*GBH + (size_t)bl*H_;
  const float* w = lw + (size_t)o*H_;
  float s = lb[o];
  #pragma unroll 8
  for (int k = 0; k < H_; ++k) s += h[k]*w[k];
  out[idx] = s;
}

extern "C" void kernel_launch(void* const* d_in, const int* in_sizes, int n_in,
                              void* d_out, int out_size, void* d_ws, size_t ws_size,
                              hipStream_t stream) {
  const float* inputs = (const float*)d_in[0];
  const float* conv_w = (const float*)d_in[3];
  const float* conv_b = (const float*)d_in[4];
  const float* w_ih   = (const float*)d_in[5];
  const float* w_hh   = (const float*)d_in[6];
  const float* b_ih   = (const float*)d_in[7];
  const float* b_hh   = (const float*)d_in[8];
  const float* lin_w  = (const float*)d_in[9];
  const float* lin_b  = (const float*)d_in[10];

  float* actT   = (float*)d_ws;
  float* hbuf   = (float*)((char*)d_ws + HBUF_OFF);
  float* hfinal = (float*)((char*)d_ws + HFINAL_OFF);

  // clear stamps each launch (replay-safe: old stamps never alias new ones)
  hipMemsetAsync(hbuf, 0, HBUF_BYTES, stream);
  hipLaunchKernelGGL(conv_kernel, dim3(B_*16), dim3(512), 192*128*4, stream,
                     inputs, conv_w, conv_b, actT);
  hipLaunchKernelGGL(lstm_kernel, dim3(NG*NCH), dim3(256), 0, stream,
                     actT, w_ih, w_hh, b_ih, b_hh, hbuf, hfinal);
  hipLaunchKernelGGL(head_kernel, dim3(3), dim3(256), 0, stream,
                     hfinal, lin_w, lin_b, (float*)d_out);
}